// Round 9
// baseline (1371.537 us; speedup 1.0000x reference)
//
#include <hip/hip_runtime.h>
#include <hip/hip_bf16.h>
#include <stdint.h>

// FT-Transformer forward, MI355X gfx950. Round 14:
//  - REVERT to round-9 structure (best measured 1269.7us): gemm_frag 128x128 / 4
//    waves / 2-buf global_load_lds / (256,4) / C^T vector epilogue; separate
//    ln_kernel + out_copy. (Both gemm_ln fusion variants lost ~30us net.)
//  - attn_kernel: fix systematic LDS bank conflicts. SP 160 -> 164:
//    bf16 row stride 164 el = 82 words == 18 mod 32 -> 16 distinct banks on PV
//    fragment reads (was 8-way conflict at stride 80==16); float stride 164 == 4
//    mod 32 -> full bank spread in softmax (was all rows on 8 banks).
//    Plus XCD-bijective blockIdx remap so each batch's 8 heads (396KB shared qkv)
//    stay on one XCD's L2.

typedef __hip_bfloat16 bf16_t;
typedef __attribute__((ext_vector_type(8))) __bf16 bf16x8;
typedef __attribute__((ext_vector_type(4))) __bf16 bf16x4;
typedef __attribute__((ext_vector_type(2))) __bf16 bf16x2;
typedef __attribute__((ext_vector_type(4))) float floatx4;

constexpr int M_ROWS = 16512;          // 128 * 129
constexpr float SQRT_EMB_F = 22.627416997969522f;  // scores DIVIDED by emb**-0.5

__device__ __forceinline__ floatx4 mfma16(bf16x8 a, bf16x8 b, floatx4 c) {
  return __builtin_amdgcn_mfma_f32_16x16x32_bf16(a, b, c, 0, 0, 0);
}

__device__ __forceinline__ void gload_lds16(const bf16_t* g, bf16_t* l) {
  __builtin_amdgcn_global_load_lds(
      (const __attribute__((address_space(1))) void*)g,
      (__attribute__((address_space(3))) void*)l, 16, 0, 0);
}

// element offset of the 16B chunk holding (m, k..k+7) in fragment-tiled [M/16][KT][512]
__device__ __forceinline__ size_t frag_chunk(int m, int k, int KT) {
  return ((size_t)(m >> 4) * KT + (k >> 5)) * 512 + (m & 15) * 8 + 128 * ((k >> 3) & 3);
}
// element offset of scalar (m, k)
__device__ __forceinline__ size_t frag_elem(int m, int k, int KT) {
  return frag_chunk(m, k, KT) + (k & 7);
}

// ---------------- weight transform: W [L][K][N] fp32 -> frag-tiled bf16 [L][N/16][KP/32][512]
// PERM=1: output col n maps to source col (n&1) ? 682+(n>>1) : (n>>1)  (ReGLU pairing)
template <int PERM>
__global__ __launch_bounds__(256) void transpose_cvt(const float* __restrict__ W,
    bf16_t* __restrict__ WT, int K, int N, int KP, int NP)
{
  __shared__ float tile[32][33];
  int k0 = blockIdx.x * 32, n0 = blockIdx.y * 32;
  const float* Wl = W + (size_t)blockIdx.z * K * N;
  bf16_t* WTl = WT + (size_t)blockIdx.z * NP * KP;
  const int KT = KP >> 5;
  #pragma unroll
  for (int r = 0; r < 32; r += 8) {
    int k = k0 + threadIdx.y + r, n = n0 + threadIdx.x;
    int srcn = PERM ? ((n & 1) ? 682 + (n >> 1) : (n >> 1)) : n;
    int valid = (k < K) && (PERM ? (n < 1364) : (n < N));
    tile[threadIdx.y + r][threadIdx.x] = valid ? Wl[(size_t)k * N + srcn] : 0.f;
  }
  __syncthreads();
  #pragma unroll
  for (int r = 0; r < 32; r += 8) {
    int n = n0 + threadIdx.y + r, k = k0 + threadIdx.x;
    if (n < NP && k < KP)
      WTl[frag_elem(n, k, KT)] = __float2bfloat16(tile[threadIdx.x][threadIdx.y + r]);
  }
}

// ---------------- feature tokenizer: wave per row; h row-major fp32 + ab frag bf16 ----------------
__global__ __launch_bounds__(256) void tokenizer_kernel(const float* __restrict__ x,
    const float* __restrict__ tok_w, const float* __restrict__ tok_b,
    const float* __restrict__ cat_emb, float* __restrict__ h, bf16_t* __restrict__ ab)
{
  int row = blockIdx.x * 4 + (threadIdx.x >> 6);
  int lane = threadIdx.x & 63, e0 = lane * 8;
  int b = row / 129, t = row - b * 129;
  float v[8];
  if (t == 0) {
    #pragma unroll
    for (int u = 0; u < 8; u++) v[u] = tok_w[e0 + u];
  } else if (t <= 100) {
    float xv = x[(size_t)b * 128 + 28 + (t - 1)];
    const float* wp = tok_w + (size_t)t * 512 + e0;
    const float* bp = tok_b + (size_t)(t - 1) * 512 + e0;
    #pragma unroll
    for (int u = 0; u < 8; u++) v[u] = wp[u] * xv + bp[u];
  } else {
    int j = t - 101;
    int idx = (int)x[(size_t)b * 128 + j] + 100 * j;
    const float* cp = cat_emb + (size_t)idx * 512 + e0;
    const float* bp = tok_b + (size_t)(t - 1) * 512 + e0;
    #pragma unroll
    for (int u = 0; u < 8; u++) v[u] = cp[u] + bp[u];
  }
  float* hr = h + (size_t)row * 512 + e0;
  #pragma unroll
  for (int u = 0; u < 8; u++) hr[u] = v[u];
  bf16x8 o8;
  #pragma unroll
  for (int u = 0; u < 8; u++) o8[u] = (__bf16)__float2bfloat16(v[u]);
  *(bf16x8*)(ab + ((size_t)(row >> 4) * 16 + (lane >> 2)) * 512 + (row & 15) * 8 + 128 * (lane & 3)) = o8;
}

// ---------------- layernorm: one wave per row; out = frag-tiled bf16 (KT=16) ----------------
__global__ __launch_bounds__(256) void ln_kernel(const float* __restrict__ hin,
    bf16_t* __restrict__ out, const float* __restrict__ g, const float* __restrict__ bta)
{
  int row = blockIdx.x * 4 + (threadIdx.x >> 6);
  int lane = threadIdx.x & 63;
  const float* hr = hin + (size_t)row * 512 + lane * 8;
  float4 v0 = *(const float4*)hr;
  float4 v1 = *(const float4*)(hr + 4);
  float s = v0.x + v0.y + v0.z + v0.w + v1.x + v1.y + v1.z + v1.w;
  float q = v0.x * v0.x + v0.y * v0.y + v0.z * v0.z + v0.w * v0.w
          + v1.x * v1.x + v1.y * v1.y + v1.z * v1.z + v1.w * v1.w;
  #pragma unroll
  for (int o = 1; o < 64; o <<= 1) { s += __shfl_xor(s, o); q += __shfl_xor(q, o); }
  float mean = s * (1.f / 512.f);
  float var = q * (1.f / 512.f) - mean * mean;
  float rstd = rsqrtf(var + 1e-5f);
  float4 g0 = *(const float4*)(g + lane * 8);
  float4 g1 = *(const float4*)(g + lane * 8 + 4);
  float4 b0v = *(const float4*)(bta + lane * 8);
  float4 b1v = *(const float4*)(bta + lane * 8 + 4);
  bf16x8 o8;
  o8[0] = (__bf16)__float2bfloat16((v0.x - mean) * rstd * g0.x + b0v.x);
  o8[1] = (__bf16)__float2bfloat16((v0.y - mean) * rstd * g0.y + b0v.y);
  o8[2] = (__bf16)__float2bfloat16((v0.z - mean) * rstd * g0.z + b0v.z);
  o8[3] = (__bf16)__float2bfloat16((v0.w - mean) * rstd * g0.w + b0v.w);
  o8[4] = (__bf16)__float2bfloat16((v1.x - mean) * rstd * g1.x + b1v.x);
  o8[5] = (__bf16)__float2bfloat16((v1.y - mean) * rstd * g1.y + b1v.y);
  o8[6] = (__bf16)__float2bfloat16((v1.z - mean) * rstd * g1.z + b1v.z);
  o8[7] = (__bf16)__float2bfloat16((v1.w - mean) * rstd * g1.w + b1v.w);
  *(bf16x8*)(out + ((size_t)(row >> 4) * 16 + (lane >> 2)) * 512 + (row & 15) * 8 + 128 * (lane & 3)) = o8;
}

// ---------------- frag GEMM: C[M,N] = A * BT^T + bias ----------------
// 128x128 block tile, 4 waves (64x64 each). 2-buf LDS + __syncthreads per K-step.
// C^T accumulation: acc = mfma(bg, af, acc) -> l15 = row, quad*4+r = col.
// MODE 0: out bf16 frag-tiled (KT_out = N/32).
// MODE 1: out fp32 row-major = resid + acc + bias (N==512==biasN).
// MODE 2: ReGLU pairs thread-local, out bf16 frag-tiled [M/16][(N/2)/32][512].
template <int MODE>
__global__ __launch_bounds__(256, 4) void gemm_frag(const bf16_t* __restrict__ A,
    const bf16_t* __restrict__ BT, const float* __restrict__ bias, int biasN,
    const float* __restrict__ resid, void* __restrict__ outp, int K, int N)
{
  __shared__ bf16_t lsA[2][8][512];   // 16 KB
  __shared__ bf16_t lsB[2][8][512];   // 16 KB

  // XCD-aware remap: blocks with lin%8==x get a contiguous idx chunk
  const int total = gridDim.x * gridDim.y;
  const int lin = blockIdx.y * gridDim.x + blockIdx.x;
  const int xcd = lin & 7, kb2 = lin >> 3;
  const int qch = total >> 3, rch = total & 7;
  const int idx = xcd * qch + (xcd < rch ? xcd : rch) + kb2;
  const int bm = idx / gridDim.x;
  const int bn = idx - bm * gridDim.x;
  const int m0 = bm * 128, n0 = bn * 128;

  const int tid = threadIdx.x;
  const int w = tid >> 6, l = tid & 63, l15 = l & 15, quad = l >> 4;
  const int wm = (w >> 1) * 64, wn = (w & 1) * 64;
  const int KT = K >> 5;

  const bf16_t* gA0 = A  + ((size_t)((m0 >> 4) + 2 * w) * KT) * 512 + l * 8;
  const bf16_t* gA1 = gA0 + (size_t)KT * 512;
  const bf16_t* gB0 = BT + ((size_t)((n0 >> 4) + 2 * w) * KT) * 512 + l * 8;
  const bf16_t* gB1 = gB0 + (size_t)KT * 512;
  const int sa = w * 2;
  const int ra = (w >> 1) * 4;
  const int rb = (w & 1) * 4;

  auto stage = [&](int buf, int t) {
    const size_t go = (size_t)t * 512;
    gload_lds16(gA0 + go, &lsA[buf][sa][0]);
    gload_lds16(gA1 + go, &lsA[buf][sa + 1][0]);
    gload_lds16(gB0 + go, &lsB[buf][sa][0]);
    gload_lds16(gB1 + go, &lsB[buf][sa + 1][0]);
  };

  floatx4 z4 = {0.f, 0.f, 0.f, 0.f};
  floatx4 acc[4][4];
  #pragma unroll
  for (int i = 0; i < 4; i++)
    #pragma unroll
    for (int j = 0; j < 4; j++) acc[i][j] = z4;

  stage(0, 0);
  __syncthreads();   // compiler drains vmcnt(0) before barrier -> buf0 ready

  int cur = 0;
  for (int t = 0; t < KT; ++t) {
    if (t + 1 < KT) stage(cur ^ 1, t + 1);   // async DMA, in flight across this step
    bf16x8 af[4], bg[4];
    #pragma unroll
    for (int i = 0; i < 4; i++) {
      af[i] = *(const bf16x8*)&lsA[cur][ra + i][l * 8];
      bg[i] = *(const bf16x8*)&lsB[cur][rb + i][l * 8];
    }
    #pragma unroll
    for (int i = 0; i < 4; i++)
      #pragma unroll
      for (int j = 0; j < 4; j++)
        acc[i][j] = mfma16(bg[j], af[i], acc[i][j]);   // C^T
    __syncthreads();   // drains vmcnt (next buf staged) + guards buf reuse
    cur ^= 1;
  }

  // epilogue: thread owns rows m = m0+wm+i*16+l15, cols nb..nb+3 (consecutive)
  #pragma unroll
  for (int i = 0; i < 4; i++) {
    int m = m0 + wm + i * 16 + l15;
    #pragma unroll
    for (int j = 0; j < 4; j++) {
      int nb = n0 + wn + j * 16 + quad * 4;
      if (MODE == 2) {
        int c2b = nb >> 1;
        bf16x2 o2;
        #pragma unroll
        for (int u = 0; u < 2; u++) {
          int c2 = c2b + u;
          bool vld = (2 * c2 < biasN);
          float av = acc[i][j][2 * u]     + (vld ? bias[c2] : 0.f);
          float bv = acc[i][j][2 * u + 1] + (vld ? bias[682 + c2] : 0.f);
          o2[u] = (__bf16)__float2bfloat16(av * fmaxf(bv, 0.f));
        }
        *(bf16x2*)&((bf16_t*)outp)[frag_elem(m, c2b, (N >> 1) >> 5)] = o2;
      } else if (MODE == 1) {
        size_t idx2 = (size_t)m * N + nb;
        float4 rv = *(const float4*)(resid + idx2);
        float4 ov;
        ov.x = acc[i][j][0] + bias[nb + 0] + rv.x;
        ov.y = acc[i][j][1] + bias[nb + 1] + rv.y;
        ov.z = acc[i][j][2] + bias[nb + 2] + rv.z;
        ov.w = acc[i][j][3] + bias[nb + 3] + rv.w;
        *(float4*)((float*)outp + idx2) = ov;
      } else {
        bf16x4 o4;
        #pragma unroll
        for (int r = 0; r < 4; r++) {
          float bv = (nb + r < biasN) ? bias[nb + r] : 0.f;
          o4[r] = (__bf16)__float2bfloat16(acc[i][j][r] + bv);
        }
        *(bf16x4*)&((bf16_t*)outp)[frag_elem(m, nb, N >> 5)] = o4;
      }
    }
  }
}

// ---------------- fused attention: one block per (batch, head) ----------------
// qkv frag-tiled over [M, 1536] (KT=48); head hh: q at col hh*192, k +64, v +128.
// SP=164: bf16 row stride 82 words == 18 mod 32 -> conflict-free PV fragment reads;
// float stride == 4 mod 32 -> conflict-free softmax row access. (SP=160 was 8-way.)
constexpr int SP = 164;  // S=129 padded (compute uses first 160 cols; 4 pad for banks)
__global__ __launch_bounds__(256) void attn_kernel(const bf16_t* __restrict__ qkv,
                                                   bf16_t* __restrict__ attnout)
{
  __shared__ bf16_t vt_lds[64 * SP];   // [d][s_kv]
  __shared__ float sc[32 * SP];        // scores; p (bf16) overlays
  bf16_t* p_lds = (bf16_t*)sc;
  __bf16* vt_raw = (__bf16*)vt_lds;

  // XCD-bijective remap: nwg=1024 -> each XCD gets 128 consecutive bh
  // (16 batches x 8 heads share that batch's 396KB qkv slice in one L2)
  const int nwg = gridDim.x;
  const int lin = blockIdx.x;
  const int xcd = lin & 7, kb2 = lin >> 3;
  const int qch = nwg >> 3, rch = nwg & 7;
  const int bh = xcd * qch + (xcd < rch ? xcd : rch) + kb2;
  const int b = bh >> 3, hh = bh & 7;
  const int tid = threadIdx.x;
  const int w = tid >> 6, l = tid & 63, l15 = l & 15, quad = l >> 4;
  const int rbase = b * 129;

  for (int i = tid; i < SP * 64 / 2; i += 256) ((unsigned int*)vt_lds)[i] = 0u;
  __syncthreads();
  for (int c = tid; c < 129 * 8; c += 256) {
    int s = c >> 3, ch = c & 7;
    bf16x8 tv = *(const bf16x8*)(qkv + frag_chunk(rbase + s, hh * 192 + 128 + ch * 8, 48));
    #pragma unroll
    for (int j = 0; j < 8; j++) vt_raw[(size_t)(ch * 8 + j) * SP + s] = tv[j];
  }
  __syncthreads();

  for (int qt = 0; qt < 5; qt++) {
    bf16x8 zq = {};
    bf16x8 aq[2][2];
    #pragma unroll
    for (int mt = 0; mt < 2; mt++) {
      int m = qt * 32 + mt * 16 + l15;
      #pragma unroll
      for (int t = 0; t < 2; t++)
        aq[mt][t] = (m < 129)
            ? *(const bf16x8*)(qkv + frag_chunk(rbase + m, hh * 192 + t * 32 + quad * 8, 48)) : zq;
    }
    for (int nt = w; nt < 10; nt += 4) {
      int krow = nt * 16 + l15;
      floatx4 a0 = {0.f, 0.f, 0.f, 0.f}, a1 = {0.f, 0.f, 0.f, 0.f};
      #pragma unroll
      for (int t = 0; t < 2; t++) {
        bf16x8 kf = (krow < 129)
            ? *(const bf16x8*)(qkv + frag_chunk(rbase + krow, hh * 192 + 64 + t * 32 + quad * 8, 48))
            : zq;
        a0 = mfma16(aq[0][t], kf, a0);
        a1 = mfma16(aq[1][t], kf, a1);
      }
      #pragma unroll
      for (int r = 0; r < 4; r++) {
        sc[(quad * 4 + r) * SP + nt * 16 + l15]      = a0[r] * SQRT_EMB_F;
        sc[(16 + quad * 4 + r) * SP + nt * 16 + l15] = a1[r] * SQRT_EMB_F;
      }
    }
    __syncthreads();

    // double softmax, 8 threads per row
    {
      int row = tid >> 3, sub = tid & 7;
      float vv[20];
      float mx = -1e30f;
      #pragma unroll
      for (int c = 0; c < 20; c++) {
        int j = sub + c * 8;
        vv[c] = (j < 129) ? sc[row * SP + j] : -1e30f;
        mx = fmaxf(mx, vv[c]);
      }
      #pragma unroll
      for (int o = 1; o < 8; o <<= 1) mx = fmaxf(mx, __shfl_xor(mx, o, 8));
      float sum = 0.f;
      #pragma unroll
      for (int c = 0; c < 20; c++) {
        int j = sub + c * 8;
        vv[c] = (j < 129) ? __expf(vv[c] - mx) : 0.f;
        sum += vv[c];
      }
      #pragma unroll
      for (int o = 1; o < 8; o <<= 1) sum += __shfl_xor(sum, o, 8);
      float inv = 1.f / sum;
      float mx2 = 0.f;
      #pragma unroll
      for (int c = 0; c < 20; c++) { vv[c] *= inv; mx2 = fmaxf(mx2, vv[c]); }
      #pragma unroll
      for (int o = 1; o < 8; o <<= 1) mx2 = fmaxf(mx2, __shfl_xor(mx2, o, 8));
      float sum2 = 0.f;
      #pragma unroll
      for (int c = 0; c < 20; c++) {
        int j = sub + c * 8;
        vv[c] = (j < 129) ? __expf(vv[c] - mx2) : 0.f;
        sum2 += vv[c];
      }
      #pragma unroll
      for (int o = 1; o < 8; o <<= 1) sum2 += __shfl_xor(sum2, o, 8);
      float inv2 = 1.f / sum2;
      __syncthreads();
      #pragma unroll
      for (int c = 0; c < 20; c++) {
        int j = sub + c * 8;
        p_lds[row * SP + j] = __float2bfloat16(vv[c] * inv2);  // pads -> 0
      }
    }
    __syncthreads();

    // PV: o[32,64] = p[32,160] @ v[160,64]; store attno in frag layout (KT=16)
    {
      int mt = w >> 1, nt0 = (w & 1) * 2;
      floatx4 oacc[2];
      oacc[0] = floatx4{0.f, 0.f, 0.f, 0.f};
      oacc[1] = floatx4{0.f, 0.f, 0.f, 0.f};
      #pragma unroll
      for (int t = 0; t < 5; t++) {
        bf16x8 pf = *(const bf16x8*)&p_lds[(mt * 16 + l15) * SP + t * 32 + quad * 8];
        #pragma unroll
        for (int n = 0; n < 2; n++) {
          bf16x8 vf = *(const bf16x8*)&vt_lds[((nt0 + n) * 16 + l15) * SP + t * 32 + quad * 8];
          oacc[n] = mfma16(pf, vf, oacc[n]);
        }
      }
      #pragma unroll
      for (int n = 0; n < 2; n++)
        #pragma unroll
        for (int r = 0; r < 4; r++) {
          int sq = qt * 32 + mt * 16 + quad * 4 + r;
          if (sq < 129) {
            int cc = hh * 64 + (nt0 + n) * 16 + l15;
            attnout[frag_elem(rbase + sq, cc, 16)] = __float2bfloat16(oacc[n][r]);
          }
        }
    }
    __syncthreads();
  }
}

// ---------------- output: CLS rows ----------------
__global__ __launch_bounds__(256) void out_copy(const float* __restrict__ h,
                                                float* __restrict__ out)
{
  int b = blockIdx.x, e = threadIdx.x;
  out[(size_t)b * 512 + e]       = h[(size_t)b * 129 * 512 + e];
  out[(size_t)b * 512 + e + 256] = h[(size_t)b * 129 * 512 + e + 256];
}

// ---------------- host launcher ----------------
extern "C" void kernel_launch(void* const* d_in, const int* in_sizes, int n_in,
                              void* d_out, int out_size, void* d_ws, size_t ws_size,
                              hipStream_t stream)
{
  const float* x       = (const float*)d_in[0];
  const float* tok_w   = (const float*)d_in[1];
  const float* tok_b   = (const float*)d_in[2];
  const float* cat_emb = (const float*)d_in[3];
  const float* Wqkv    = (const float*)d_in[4];
  const float* bqkv    = (const float*)d_in[5];
  const float* Wout    = (const float*)d_in[6];
  const float* bout    = (const float*)d_in[7];
  const float* W0      = (const float*)d_in[8];
  const float* b0      = (const float*)d_in[9];
  const float* W1      = (const float*)d_in[10];
  const float* b1      = (const float*)d_in[11];
  const float* ln0_g   = (const float*)d_in[12];
  const float* ln0_b   = (const float*)d_in[13];
  const float* ln1_g   = (const float*)d_in[14];
  const float* ln1_b   = (const float*)d_in[15];

  size_t off = 0;
  char* base = (char*)d_ws;
  auto alloc = [&](size_t n) { char* p = base + off; off += (n + 255) & ~(size_t)255; return p; };
  float*  h     = (float*) alloc((size_t)M_ROWS * 512 * 4);
  bf16_t* ab    = (bf16_t*)alloc((size_t)M_ROWS * 512 * 2);   // LN out, frag KT=16
  bf16_t* qkv   = (bf16_t*)alloc((size_t)M_ROWS * 1536 * 2);  // frag KT=48
  bf16_t* attno = (bf16_t*)alloc((size_t)M_ROWS * 512 * 2);   // frag KT=16
  bf16_t* regl  = (bf16_t*)alloc((size_t)M_ROWS * 704 * 2);   // frag KT=22
  bf16_t* WqkvT = (bf16_t*)alloc((size_t)6 * 1536 * 512 * 2);
  bf16_t* WoutT = (bf16_t*)alloc((size_t)6 * 512 * 512 * 2);
  bf16_t* W0T   = (bf16_t*)alloc((size_t)6 * 1408 * 512 * 2);  // pair-interleaved
  bf16_t* W1T   = (bf16_t*)alloc((size_t)6 * 512 * 704 * 2);
  (void)ws_size; (void)in_sizes; (void)n_in; (void)out_size;

  dim3 tb(32, 8, 1);
  transpose_cvt<0><<<dim3(16, 48, 6), tb, 0, stream>>>(Wqkv, WqkvT, 512, 1536, 512, 1536);
  transpose_cvt<0><<<dim3(16, 16, 6), tb, 0, stream>>>(Wout, WoutT, 512, 512, 512, 512);
  transpose_cvt<1><<<dim3(16, 44, 6), tb, 0, stream>>>(W0, W0T, 512, 1364, 512, 1408);
  transpose_cvt<0><<<dim3(22, 16, 6), tb, 0, stream>>>(W1, W1T, 682, 512, 704, 512);

  tokenizer_kernel<<<M_ROWS / 4, 256, 0, stream>>>(x, tok_w, tok_b, cat_emb, h, ab);

  for (int i = 0; i < 6; i++) {
    if (i)
      ln_kernel<<<M_ROWS / 4, 256, 0, stream>>>(h, ab, ln0_g + (size_t)i * 512,
                                                ln0_b + (size_t)i * 512);
    gemm_frag<0><<<dim3(12, 129), 256, 0, stream>>>(
        ab, WqkvT + (size_t)i * 1536 * 512, bqkv + (size_t)i * 1536, 1536, nullptr, qkv, 512, 1536);
    attn_kernel<<<1024, 256, 0, stream>>>(qkv, attno);
    gemm_frag<1><<<dim3(4, 129), 256, 0, stream>>>(
        attno, WoutT + (size_t)i * 512 * 512, bout + (size_t)i * 512, 512, h, h, 512, 512);
    ln_kernel<<<M_ROWS / 4, 256, 0, stream>>>(h, ab, ln1_g + (size_t)i * 512,
                                              ln1_b + (size_t)i * 512);
    gemm_frag<2><<<dim3(11, 129), 256, 0, stream>>>(
        ab, W0T + (size_t)i * 1408 * 512, b0 + (size_t)i * 1364, 1364, nullptr, regl, 512, 1408);
    gemm_frag<1><<<dim3(4, 129), 256, 0, stream>>>(
        regl, W1T + (size_t)i * 512 * 704, b1 + (size_t)i * 512, 512, h, h, 704, 512);
  }

  out_copy<<<128, 256, 0, stream>>>(h, (float*)d_out);
}

// Round 10
// 1355.464 us; speedup vs baseline: 1.0119x; 1.0119x over previous
//
#include <hip/hip_runtime.h>
#include <hip/hip_bf16.h>
#include <stdint.h>

// FT-Transformer forward, MI355X gfx950. Round 15:
//  - Base = round-9/round-4 best (1269.7us): gemm_frag 128x128 / 4 waves / 2-buf
//    global_load_lds / (256,4) / C^T vector epilogue; separate ln_kernel + out_copy;
//    attn SP=160, natural block order (round-14's SP=164 + XCD remap regressed).
//  - attn: cut barrier chain 22 -> 12. p_lds DE-ALIASED from sc (own 10KB buffer)
//    which makes the pre-p-write and post-PV barriers redundant (PV p-reads are
//    ordered against next qt's p-writes by the next scores-barrier). 2 barriers/qt.
//  - attn: analytic 2nd softmax max: max(p1) = 1/Z1 exactly (argmax term = e^0/Z1),
//    so pass-2 becomes w = exp((u-1)*invZ1) -- second max-reduce + normalize-mul
//    removed. Exact equivalence; (u-1)/Z1 in [-1,0].

typedef __hip_bfloat16 bf16_t;
typedef __attribute__((ext_vector_type(8))) __bf16 bf16x8;
typedef __attribute__((ext_vector_type(4))) __bf16 bf16x4;
typedef __attribute__((ext_vector_type(2))) __bf16 bf16x2;
typedef __attribute__((ext_vector_type(4))) float floatx4;

constexpr int M_ROWS = 16512;          // 128 * 129
constexpr float SQRT_EMB_F = 22.627416997969522f;  // scores DIVIDED by emb**-0.5

__device__ __forceinline__ floatx4 mfma16(bf16x8 a, bf16x8 b, floatx4 c) {
  return __builtin_amdgcn_mfma_f32_16x16x32_bf16(a, b, c, 0, 0, 0);
}

__device__ __forceinline__ void gload_lds16(const bf16_t* g, bf16_t* l) {
  __builtin_amdgcn_global_load_lds(
      (const __attribute__((address_space(1))) void*)g,
      (__attribute__((address_space(3))) void*)l, 16, 0, 0);
}

// element offset of the 16B chunk holding (m, k..k+7) in fragment-tiled [M/16][KT][512]
__device__ __forceinline__ size_t frag_chunk(int m, int k, int KT) {
  return ((size_t)(m >> 4) * KT + (k >> 5)) * 512 + (m & 15) * 8 + 128 * ((k >> 3) & 3);
}
// element offset of scalar (m, k)
__device__ __forceinline__ size_t frag_elem(int m, int k, int KT) {
  return frag_chunk(m, k, KT) + (k & 7);
}

// ---------------- weight transform: W [L][K][N] fp32 -> frag-tiled bf16 [L][N/16][KP/32][512]
// PERM=1: output col n maps to source col (n&1) ? 682+(n>>1) : (n>>1)  (ReGLU pairing)
template <int PERM>
__global__ __launch_bounds__(256) void transpose_cvt(const float* __restrict__ W,
    bf16_t* __restrict__ WT, int K, int N, int KP, int NP)
{
  __shared__ float tile[32][33];
  int k0 = blockIdx.x * 32, n0 = blockIdx.y * 32;
  const float* Wl = W + (size_t)blockIdx.z * K * N;
  bf16_t* WTl = WT + (size_t)blockIdx.z * NP * KP;
  const int KT = KP >> 5;
  #pragma unroll
  for (int r = 0; r < 32; r += 8) {
    int k = k0 + threadIdx.y + r, n = n0 + threadIdx.x;
    int srcn = PERM ? ((n & 1) ? 682 + (n >> 1) : (n >> 1)) : n;
    int valid = (k < K) && (PERM ? (n < 1364) : (n < N));
    tile[threadIdx.y + r][threadIdx.x] = valid ? Wl[(size_t)k * N + srcn] : 0.f;
  }
  __syncthreads();
  #pragma unroll
  for (int r = 0; r < 32; r += 8) {
    int n = n0 + threadIdx.y + r, k = k0 + threadIdx.x;
    if (n < NP && k < KP)
      WTl[frag_elem(n, k, KT)] = __float2bfloat16(tile[threadIdx.x][threadIdx.y + r]);
  }
}

// ---------------- feature tokenizer: wave per row; h row-major fp32 + ab frag bf16 ----------------
__global__ __launch_bounds__(256) void tokenizer_kernel(const float* __restrict__ x,
    const float* __restrict__ tok_w, const float* __restrict__ tok_b,
    const float* __restrict__ cat_emb, float* __restrict__ h, bf16_t* __restrict__ ab)
{
  int row = blockIdx.x * 4 + (threadIdx.x >> 6);
  int lane = threadIdx.x & 63, e0 = lane * 8;
  int b = row / 129, t = row - b * 129;
  float v[8];
  if (t == 0) {
    #pragma unroll
    for (int u = 0; u < 8; u++) v[u] = tok_w[e0 + u];
  } else if (t <= 100) {
    float xv = x[(size_t)b * 128 + 28 + (t - 1)];
    const float* wp = tok_w + (size_t)t * 512 + e0;
    const float* bp = tok_b + (size_t)(t - 1) * 512 + e0;
    #pragma unroll
    for (int u = 0; u < 8; u++) v[u] = wp[u] * xv + bp[u];
  } else {
    int j = t - 101;
    int idx = (int)x[(size_t)b * 128 + j] + 100 * j;
    const float* cp = cat_emb + (size_t)idx * 512 + e0;
    const float* bp = tok_b + (size_t)(t - 1) * 512 + e0;
    #pragma unroll
    for (int u = 0; u < 8; u++) v[u] = cp[u] + bp[u];
  }
  float* hr = h + (size_t)row * 512 + e0;
  #pragma unroll
  for (int u = 0; u < 8; u++) hr[u] = v[u];
  bf16x8 o8;
  #pragma unroll
  for (int u = 0; u < 8; u++) o8[u] = (__bf16)__float2bfloat16(v[u]);
  *(bf16x8*)(ab + ((size_t)(row >> 4) * 16 + (lane >> 2)) * 512 + (row & 15) * 8 + 128 * (lane & 3)) = o8;
}

// ---------------- layernorm: one wave per row; out = frag-tiled bf16 (KT=16) ----------------
__global__ __launch_bounds__(256) void ln_kernel(const float* __restrict__ hin,
    bf16_t* __restrict__ out, const float* __restrict__ g, const float* __restrict__ bta)
{
  int row = blockIdx.x * 4 + (threadIdx.x >> 6);
  int lane = threadIdx.x & 63;
  const float* hr = hin + (size_t)row * 512 + lane * 8;
  float4 v0 = *(const float4*)hr;
  float4 v1 = *(const float4*)(hr + 4);
  float s = v0.x + v0.y + v0.z + v0.w + v1.x + v1.y + v1.z + v1.w;
  float q = v0.x * v0.x + v0.y * v0.y + v0.z * v0.z + v0.w * v0.w
          + v1.x * v1.x + v1.y * v1.y + v1.z * v1.z + v1.w * v1.w;
  #pragma unroll
  for (int o = 1; o < 64; o <<= 1) { s += __shfl_xor(s, o); q += __shfl_xor(q, o); }
  float mean = s * (1.f / 512.f);
  float var = q * (1.f / 512.f) - mean * mean;
  float rstd = rsqrtf(var + 1e-5f);
  float4 g0 = *(const float4*)(g + lane * 8);
  float4 g1 = *(const float4*)(g + lane * 8 + 4);
  float4 b0v = *(const float4*)(bta + lane * 8);
  float4 b1v = *(const float4*)(bta + lane * 8 + 4);
  bf16x8 o8;
  o8[0] = (__bf16)__float2bfloat16((v0.x - mean) * rstd * g0.x + b0v.x);
  o8[1] = (__bf16)__float2bfloat16((v0.y - mean) * rstd * g0.y + b0v.y);
  o8[2] = (__bf16)__float2bfloat16((v0.z - mean) * rstd * g0.z + b0v.z);
  o8[3] = (__bf16)__float2bfloat16((v0.w - mean) * rstd * g0.w + b0v.w);
  o8[4] = (__bf16)__float2bfloat16((v1.x - mean) * rstd * g1.x + b1v.x);
  o8[5] = (__bf16)__float2bfloat16((v1.y - mean) * rstd * g1.y + b1v.y);
  o8[6] = (__bf16)__float2bfloat16((v1.z - mean) * rstd * g1.z + b1v.z);
  o8[7] = (__bf16)__float2bfloat16((v1.w - mean) * rstd * g1.w + b1v.w);
  *(bf16x8*)(out + ((size_t)(row >> 4) * 16 + (lane >> 2)) * 512 + (row & 15) * 8 + 128 * (lane & 3)) = o8;
}

// ---------------- frag GEMM: C[M,N] = A * BT^T + bias ----------------
// 128x128 block tile, 4 waves (64x64 each). 2-buf LDS + __syncthreads per K-step.
// C^T accumulation: acc = mfma(bg, af, acc) -> l15 = row, quad*4+r = col.
// MODE 0: out bf16 frag-tiled (KT_out = N/32).
// MODE 1: out fp32 row-major = resid + acc + bias (N==512==biasN).
// MODE 2: ReGLU pairs thread-local, out bf16 frag-tiled [M/16][(N/2)/32][512].
template <int MODE>
__global__ __launch_bounds__(256, 4) void gemm_frag(const bf16_t* __restrict__ A,
    const bf16_t* __restrict__ BT, const float* __restrict__ bias, int biasN,
    const float* __restrict__ resid, void* __restrict__ outp, int K, int N)
{
  __shared__ bf16_t lsA[2][8][512];   // 16 KB
  __shared__ bf16_t lsB[2][8][512];   // 16 KB

  // XCD-aware remap: blocks with lin%8==x get a contiguous idx chunk
  const int total = gridDim.x * gridDim.y;
  const int lin = blockIdx.y * gridDim.x + blockIdx.x;
  const int xcd = lin & 7, kb2 = lin >> 3;
  const int qch = total >> 3, rch = total & 7;
  const int idx = xcd * qch + (xcd < rch ? xcd : rch) + kb2;
  const int bm = idx / gridDim.x;
  const int bn = idx - bm * gridDim.x;
  const int m0 = bm * 128, n0 = bn * 128;

  const int tid = threadIdx.x;
  const int w = tid >> 6, l = tid & 63, l15 = l & 15, quad = l >> 4;
  const int wm = (w >> 1) * 64, wn = (w & 1) * 64;
  const int KT = K >> 5;

  const bf16_t* gA0 = A  + ((size_t)((m0 >> 4) + 2 * w) * KT) * 512 + l * 8;
  const bf16_t* gA1 = gA0 + (size_t)KT * 512;
  const bf16_t* gB0 = BT + ((size_t)((n0 >> 4) + 2 * w) * KT) * 512 + l * 8;
  const bf16_t* gB1 = gB0 + (size_t)KT * 512;
  const int sa = w * 2;
  const int ra = (w >> 1) * 4;
  const int rb = (w & 1) * 4;

  auto stage = [&](int buf, int t) {
    const size_t go = (size_t)t * 512;
    gload_lds16(gA0 + go, &lsA[buf][sa][0]);
    gload_lds16(gA1 + go, &lsA[buf][sa + 1][0]);
    gload_lds16(gB0 + go, &lsB[buf][sa][0]);
    gload_lds16(gB1 + go, &lsB[buf][sa + 1][0]);
  };

  floatx4 z4 = {0.f, 0.f, 0.f, 0.f};
  floatx4 acc[4][4];
  #pragma unroll
  for (int i = 0; i < 4; i++)
    #pragma unroll
    for (int j = 0; j < 4; j++) acc[i][j] = z4;

  stage(0, 0);
  __syncthreads();   // compiler drains vmcnt(0) before barrier -> buf0 ready

  int cur = 0;
  for (int t = 0; t < KT; ++t) {
    if (t + 1 < KT) stage(cur ^ 1, t + 1);   // async DMA, in flight across this step
    bf16x8 af[4], bg[4];
    #pragma unroll
    for (int i = 0; i < 4; i++) {
      af[i] = *(const bf16x8*)&lsA[cur][ra + i][l * 8];
      bg[i] = *(const bf16x8*)&lsB[cur][rb + i][l * 8];
    }
    #pragma unroll
    for (int i = 0; i < 4; i++)
      #pragma unroll
      for (int j = 0; j < 4; j++)
        acc[i][j] = mfma16(bg[j], af[i], acc[i][j]);   // C^T
    __syncthreads();   // drains vmcnt (next buf staged) + guards buf reuse
    cur ^= 1;
  }

  // epilogue: thread owns rows m = m0+wm+i*16+l15, cols nb..nb+3 (consecutive)
  #pragma unroll
  for (int i = 0; i < 4; i++) {
    int m = m0 + wm + i * 16 + l15;
    #pragma unroll
    for (int j = 0; j < 4; j++) {
      int nb = n0 + wn + j * 16 + quad * 4;
      if (MODE == 2) {
        int c2b = nb >> 1;
        bf16x2 o2;
        #pragma unroll
        for (int u = 0; u < 2; u++) {
          int c2 = c2b + u;
          bool vld = (2 * c2 < biasN);
          float av = acc[i][j][2 * u]     + (vld ? bias[c2] : 0.f);
          float bv = acc[i][j][2 * u + 1] + (vld ? bias[682 + c2] : 0.f);
          o2[u] = (__bf16)__float2bfloat16(av * fmaxf(bv, 0.f));
        }
        *(bf16x2*)&((bf16_t*)outp)[frag_elem(m, c2b, (N >> 1) >> 5)] = o2;
      } else if (MODE == 1) {
        size_t idx2 = (size_t)m * N + nb;
        float4 rv = *(const float4*)(resid + idx2);
        float4 ov;
        ov.x = acc[i][j][0] + bias[nb + 0] + rv.x;
        ov.y = acc[i][j][1] + bias[nb + 1] + rv.y;
        ov.z = acc[i][j][2] + bias[nb + 2] + rv.z;
        ov.w = acc[i][j][3] + bias[nb + 3] + rv.w;
        *(float4*)((float*)outp + idx2) = ov;
      } else {
        bf16x4 o4;
        #pragma unroll
        for (int r = 0; r < 4; r++) {
          float bv = (nb + r < biasN) ? bias[nb + r] : 0.f;
          o4[r] = (__bf16)__float2bfloat16(acc[i][j][r] + bv);
        }
        *(bf16x4*)&((bf16_t*)outp)[frag_elem(m, nb, N >> 5)] = o4;
      }
    }
  }
}

// ---------------- fused attention: one block per (batch, head) ----------------
// qkv frag-tiled over [M, 1536] (KT=48); head hh: q at col hh*192, k +64, v +128.
// p_lds is its own buffer (NOT aliasing sc) -> only 2 barriers per qt:
//  (1) after scores-write (QK writers vs softmax readers)
//  (2) after p-write (softmax writers vs PV readers); this same barrier also orders
//      this qt's sc-reads before next qt's sc-writes, and next qt's scores-barrier
//      orders this qt's PV p-reads before next qt's p-writes.
constexpr int SP = 160;  // S=129 padded to 5*32
__global__ __launch_bounds__(256) void attn_kernel(const bf16_t* __restrict__ qkv,
                                                   bf16_t* __restrict__ attnout)
{
  __shared__ bf16_t vt_lds[64 * SP];   // [d][s_kv]  20.0 KB
  __shared__ float sc[32 * SP];        // scores     20.0 KB
  __shared__ bf16_t p_lds[32 * SP];    // probs      10.0 KB (de-aliased)
  __bf16* vt_raw = (__bf16*)vt_lds;

  const int bh = blockIdx.x, b = bh >> 3, hh = bh & 7;
  const int tid = threadIdx.x;
  const int w = tid >> 6, l = tid & 63, l15 = l & 15, quad = l >> 4;
  const int rbase = b * 129;

  for (int i = tid; i < SP * 64 / 2; i += 256) ((unsigned int*)vt_lds)[i] = 0u;
  __syncthreads();
  for (int c = tid; c < 129 * 8; c += 256) {
    int s = c >> 3, ch = c & 7;
    bf16x8 tv = *(const bf16x8*)(qkv + frag_chunk(rbase + s, hh * 192 + 128 + ch * 8, 48));
    #pragma unroll
    for (int j = 0; j < 8; j++) vt_raw[(size_t)(ch * 8 + j) * SP + s] = tv[j];
  }
  __syncthreads();

  for (int qt = 0; qt < 5; qt++) {
    bf16x8 zq = {};
    bf16x8 aq[2][2];
    #pragma unroll
    for (int mt = 0; mt < 2; mt++) {
      int m = qt * 32 + mt * 16 + l15;
      #pragma unroll
      for (int t = 0; t < 2; t++)
        aq[mt][t] = (m < 129)
            ? *(const bf16x8*)(qkv + frag_chunk(rbase + m, hh * 192 + t * 32 + quad * 8, 48)) : zq;
    }
    for (int nt = w; nt < 10; nt += 4) {
      int krow = nt * 16 + l15;
      floatx4 a0 = {0.f, 0.f, 0.f, 0.f}, a1 = {0.f, 0.f, 0.f, 0.f};
      #pragma unroll
      for (int t = 0; t < 2; t++) {
        bf16x8 kf = (krow < 129)
            ? *(const bf16x8*)(qkv + frag_chunk(rbase + krow, hh * 192 + 64 + t * 32 + quad * 8, 48))
            : zq;
        a0 = mfma16(aq[0][t], kf, a0);
        a1 = mfma16(aq[1][t], kf, a1);
      }
      #pragma unroll
      for (int r = 0; r < 4; r++) {
        sc[(quad * 4 + r) * SP + nt * 16 + l15]      = a0[r] * SQRT_EMB_F;
        sc[(16 + quad * 4 + r) * SP + nt * 16 + l15] = a1[r] * SQRT_EMB_F;
      }
    }
    __syncthreads();   // barrier 1: scores ready

    // double softmax, 8 threads per row.
    // softmax2 of softmax1: u = exp(s - m1), Z1 = sum u; p1 = u/Z1; max(p1) = 1/Z1
    // exactly (argmax term e^0/Z1), so pass 2 is w = exp((u-1)/Z1), out = w/sum(w).
    {
      int row = tid >> 3, sub = tid & 7;
      float vv[20];
      float mx = -1e30f;
      #pragma unroll
      for (int c = 0; c < 20; c++) {
        int j = sub + c * 8;
        vv[c] = (j < 129) ? sc[row * SP + j] : -1e30f;
        mx = fmaxf(mx, vv[c]);
      }
      #pragma unroll
      for (int o = 1; o < 8; o <<= 1) mx = fmaxf(mx, __shfl_xor(mx, o, 8));
      float sum = 0.f;
      #pragma unroll
      for (int c = 0; c < 20; c++) {
        int j = sub + c * 8;
        vv[c] = (j < 129) ? __expf(vv[c] - mx) : 0.f;
        sum += vv[c];
      }
      #pragma unroll
      for (int o = 1; o < 8; o <<= 1) sum += __shfl_xor(sum, o, 8);
      float inv = 1.f / sum;       // = max(p1), and 1/Z1 scale
      float sum2 = 0.f;
      #pragma unroll
      for (int c = 0; c < 20; c++) {
        int j = sub + c * 8;
        vv[c] = (j < 129) ? __expf((vv[c] - 1.f) * inv) : 0.f;
        sum2 += vv[c];
      }
      #pragma unroll
      for (int o = 1; o < 8; o <<= 1) sum2 += __shfl_xor(sum2, o, 8);
      float inv2 = 1.f / sum2;
      #pragma unroll
      for (int c = 0; c < 20; c++) {
        int j = sub + c * 8;
        p_lds[row * SP + j] = __float2bfloat16(vv[c] * inv2);  // pads -> 0
      }
    }
    __syncthreads();   // barrier 2: p ready (also orders sc reads vs next qt writes)

    // PV: o[32,64] = p[32,160] @ v[160,64]; store attno in frag layout (KT=16)
    {
      int mt = w >> 1, nt0 = (w & 1) * 2;
      floatx4 oacc[2];
      oacc[0] = floatx4{0.f, 0.f, 0.f, 0.f};
      oacc[1] = floatx4{0.f, 0.f, 0.f, 0.f};
      #pragma unroll
      for (int t = 0; t < 5; t++) {
        bf16x8 pf = *(const bf16x8*)&p_lds[(mt * 16 + l15) * SP + t * 32 + quad * 8];
        #pragma unroll
        for (int n = 0; n < 2; n++) {
          bf16x8 vf = *(const bf16x8*)&vt_lds[((nt0 + n) * 16 + l15) * SP + t * 32 + quad * 8];
          oacc[n] = mfma16(pf, vf, oacc[n]);
        }
      }
      #pragma unroll
      for (int n = 0; n < 2; n++)
        #pragma unroll
        for (int r = 0; r < 4; r++) {
          int sq = qt * 32 + mt * 16 + quad * 4 + r;
          if (sq < 129) {
            int cc = hh * 64 + (nt0 + n) * 16 + l15;
            attnout[frag_elem(rbase + sq, cc, 16)] = __float2bfloat16(oacc[n][r]);
          }
        }
    }
    // no barrier: next qt's scores-barrier orders PV p-reads vs next p-writes
  }
}

// ---------------- output: CLS rows ----------------
__global__ __launch_bounds__(256) void out_copy(const float* __restrict__ h,
                                                float* __restrict__ out)
{
  int b = blockIdx.x, e = threadIdx.x;
  out[(size_t)b * 512 + e]       = h[(size_t)b * 129 * 512 + e];
  out[(size_t)b * 512 + e + 256] = h[(size_t)b * 129 * 512 + e + 256];
}

// ---------------- host launcher ----------------
extern "C" void kernel_launch(void* const* d_in, const int* in_sizes, int n_in,
                              void* d_out, int out_size, void* d_ws, size_t ws_size,
                              hipStream_t stream)
{
  const float* x       = (const float*)d_in[0];
  const float* tok_w   = (const float*)d_in[1];
  const float* tok_b   = (const float*)d_in[2];
  const float* cat_emb = (const float*)d_in[3];
  const float* Wqkv    = (const float*)d_in[4];
  const float* bqkv    = (const float*)d_in[5];
  const float* Wout    = (const float*)d_in[6];
  const float* bout    = (const float*)d_in[7];
  const float* W0      = (const float*)d_in[8];
  const float* b0      = (const float*)d_in[9];
  const float* W1      = (const float*)d_in[10];
  const float* b1      = (const float*)d_in[11];
  const float* ln0_g   = (const float*)d_in[12];
  const float* ln0_b   = (const float*)d_in[13];
  const float* ln1_g   = (const float*)d_in[14];
  const float* ln1_b   = (const float*)d_in[15];

  size_t off = 0;
  char* base = (char*)d_ws;
  auto alloc = [&](size_t n) { char* p = base + off; off += (n + 255) & ~(size_t)255; return p; };
  float*  h     = (float*) alloc((size_t)M_ROWS * 512 * 4);
  bf16_t* ab    = (bf16_t*)alloc((size_t)M_ROWS * 512 * 2);   // LN out, frag KT=16
  bf16_t* qkv   = (bf16_t*)alloc((size_t)M_ROWS * 1536 * 2);  // frag KT=48
  bf16_t* attno = (bf16_t*)alloc((size_t)M_ROWS * 512 * 2);   // frag KT=16
  bf16_t* regl  = (bf16_t*)alloc((size_t)M_ROWS * 704 * 2);   // frag KT=22
  bf16_t* WqkvT = (bf16_t*)alloc((size_t)6 * 1536 * 512 * 2);
  bf16_t* WoutT = (bf16_t*)alloc((size_t)6 * 512 * 512 * 2);
  bf16_t* W0T   = (bf16_t*)alloc((size_t)6 * 1408 * 512 * 2);  // pair-interleaved
  bf16_t* W1T   = (bf16_t*)alloc((size_t)6 * 512 * 704 * 2);
  (void)ws_size; (void)in_sizes; (void)n_in; (void)out_size;

  dim3 tb(32, 8, 1);
  transpose_cvt<0><<<dim3(16, 48, 6), tb, 0, stream>>>(Wqkv, WqkvT, 512, 1536, 512, 1536);
  transpose_cvt<0><<<dim3(16, 16, 6), tb, 0, stream>>>(Wout, WoutT, 512, 512, 512, 512);
  transpose_cvt<1><<<dim3(16, 44, 6), tb, 0, stream>>>(W0, W0T, 512, 1364, 512, 1408);
  transpose_cvt<0><<<dim3(22, 16, 6), tb, 0, stream>>>(W1, W1T, 682, 512, 704, 512);

  tokenizer_kernel<<<M_ROWS / 4, 256, 0, stream>>>(x, tok_w, tok_b, cat_emb, h, ab);

  for (int i = 0; i < 6; i++) {
    if (i)
      ln_kernel<<<M_ROWS / 4, 256, 0, stream>>>(h, ab, ln0_g + (size_t)i * 512,
                                                ln0_b + (size_t)i * 512);
    gemm_frag<0><<<dim3(12, 129), 256, 0, stream>>>(
        ab, WqkvT + (size_t)i * 1536 * 512, bqkv + (size_t)i * 1536, 1536, nullptr, qkv, 512, 1536);
    attn_kernel<<<1024, 256, 0, stream>>>(qkv, attno);
    gemm_frag<1><<<dim3(4, 129), 256, 0, stream>>>(
        attno, WoutT + (size_t)i * 512 * 512, bout + (size_t)i * 512, 512, h, h, 512, 512);
    ln_kernel<<<M_ROWS / 4, 256, 0, stream>>>(h, ab, ln1_g + (size_t)i * 512,
                                              ln1_b + (size_t)i * 512);
    gemm_frag<2><<<dim3(11, 129), 256, 0, stream>>>(
        ab, W0T + (size_t)i * 1408 * 512, b0 + (size_t)i * 1364, 1364, nullptr, regl, 512, 1408);
    gemm_frag<1><<<dim3(4, 129), 256, 0, stream>>>(
        regl, W1T + (size_t)i * 512 * 704, b1 + (size_t)i * 512, 512, h, h, 704, 512);
  }

  out_copy<<<128, 256, 0, stream>>>(h, (float*)d_out);
}

// Round 11
// 1279.917 us; speedup vs baseline: 1.0716x; 1.0590x over previous
//
#include <hip/hip_runtime.h>
#include <hip/hip_bf16.h>
#include <stdint.h>

// FT-Transformer forward, MI355X gfx950. Round 16:
//  - EXACT round-4/round-9 best structure (1269.7us). attn restored to the aliased
//    p/sc overlay (LDS = 40960 B exactly -> 4 blocks/CU, the property that made it
//    fast; r14/r15 attn variants broke it) with original 4-barrier/qt chain.
//  - attn softmax: analytic 2nd max only (max(p1) = 1/Z1 exactly, argmax term
//    e^0/Z1) -> pass 2 is w = exp((u-1)*invZ1); removes one 3-shuffle max-reduce
//    + 20 muls per thread per qt. Pure VALU removal, no layout/sync change.
//  - out_copy folded into the last W1 gemm_frag (MODE 3 = MODE 1 + CLS rows to
//    d_out): one fewer dispatch + launch gap.

typedef __hip_bfloat16 bf16_t;
typedef __attribute__((ext_vector_type(8))) __bf16 bf16x8;
typedef __attribute__((ext_vector_type(4))) __bf16 bf16x4;
typedef __attribute__((ext_vector_type(2))) __bf16 bf16x2;
typedef __attribute__((ext_vector_type(4))) float floatx4;

constexpr int M_ROWS = 16512;          // 128 * 129
constexpr float SQRT_EMB_F = 22.627416997969522f;  // scores DIVIDED by emb**-0.5

__device__ __forceinline__ floatx4 mfma16(bf16x8 a, bf16x8 b, floatx4 c) {
  return __builtin_amdgcn_mfma_f32_16x16x32_bf16(a, b, c, 0, 0, 0);
}

__device__ __forceinline__ void gload_lds16(const bf16_t* g, bf16_t* l) {
  __builtin_amdgcn_global_load_lds(
      (const __attribute__((address_space(1))) void*)g,
      (__attribute__((address_space(3))) void*)l, 16, 0, 0);
}

// element offset of the 16B chunk holding (m, k..k+7) in fragment-tiled [M/16][KT][512]
__device__ __forceinline__ size_t frag_chunk(int m, int k, int KT) {
  return ((size_t)(m >> 4) * KT + (k >> 5)) * 512 + (m & 15) * 8 + 128 * ((k >> 3) & 3);
}
// element offset of scalar (m, k)
__device__ __forceinline__ size_t frag_elem(int m, int k, int KT) {
  return frag_chunk(m, k, KT) + (k & 7);
}

// ---------------- weight transform: W [L][K][N] fp32 -> frag-tiled bf16 [L][N/16][KP/32][512]
// PERM=1: output col n maps to source col (n&1) ? 682+(n>>1) : (n>>1)  (ReGLU pairing)
template <int PERM>
__global__ __launch_bounds__(256) void transpose_cvt(const float* __restrict__ W,
    bf16_t* __restrict__ WT, int K, int N, int KP, int NP)
{
  __shared__ float tile[32][33];
  int k0 = blockIdx.x * 32, n0 = blockIdx.y * 32;
  const float* Wl = W + (size_t)blockIdx.z * K * N;
  bf16_t* WTl = WT + (size_t)blockIdx.z * NP * KP;
  const int KT = KP >> 5;
  #pragma unroll
  for (int r = 0; r < 32; r += 8) {
    int k = k0 + threadIdx.y + r, n = n0 + threadIdx.x;
    int srcn = PERM ? ((n & 1) ? 682 + (n >> 1) : (n >> 1)) : n;
    int valid = (k < K) && (PERM ? (n < 1364) : (n < N));
    tile[threadIdx.y + r][threadIdx.x] = valid ? Wl[(size_t)k * N + srcn] : 0.f;
  }
  __syncthreads();
  #pragma unroll
  for (int r = 0; r < 32; r += 8) {
    int n = n0 + threadIdx.y + r, k = k0 + threadIdx.x;
    if (n < NP && k < KP)
      WTl[frag_elem(n, k, KT)] = __float2bfloat16(tile[threadIdx.x][threadIdx.y + r]);
  }
}

// ---------------- feature tokenizer: wave per row; h row-major fp32 + ab frag bf16 ----------------
__global__ __launch_bounds__(256) void tokenizer_kernel(const float* __restrict__ x,
    const float* __restrict__ tok_w, const float* __restrict__ tok_b,
    const float* __restrict__ cat_emb, float* __restrict__ h, bf16_t* __restrict__ ab)
{
  int row = blockIdx.x * 4 + (threadIdx.x >> 6);
  int lane = threadIdx.x & 63, e0 = lane * 8;
  int b = row / 129, t = row - b * 129;
  float v[8];
  if (t == 0) {
    #pragma unroll
    for (int u = 0; u < 8; u++) v[u] = tok_w[e0 + u];
  } else if (t <= 100) {
    float xv = x[(size_t)b * 128 + 28 + (t - 1)];
    const float* wp = tok_w + (size_t)t * 512 + e0;
    const float* bp = tok_b + (size_t)(t - 1) * 512 + e0;
    #pragma unroll
    for (int u = 0; u < 8; u++) v[u] = wp[u] * xv + bp[u];
  } else {
    int j = t - 101;
    int idx = (int)x[(size_t)b * 128 + j] + 100 * j;
    const float* cp = cat_emb + (size_t)idx * 512 + e0;
    const float* bp = tok_b + (size_t)(t - 1) * 512 + e0;
    #pragma unroll
    for (int u = 0; u < 8; u++) v[u] = cp[u] + bp[u];
  }
  float* hr = h + (size_t)row * 512 + e0;
  #pragma unroll
  for (int u = 0; u < 8; u++) hr[u] = v[u];
  bf16x8 o8;
  #pragma unroll
  for (int u = 0; u < 8; u++) o8[u] = (__bf16)__float2bfloat16(v[u]);
  *(bf16x8*)(ab + ((size_t)(row >> 4) * 16 + (lane >> 2)) * 512 + (row & 15) * 8 + 128 * (lane & 3)) = o8;
}

// ---------------- layernorm: one wave per row; out = frag-tiled bf16 (KT=16) ----------------
__global__ __launch_bounds__(256) void ln_kernel(const float* __restrict__ hin,
    bf16_t* __restrict__ out, const float* __restrict__ g, const float* __restrict__ bta)
{
  int row = blockIdx.x * 4 + (threadIdx.x >> 6);
  int lane = threadIdx.x & 63;
  const float* hr = hin + (size_t)row * 512 + lane * 8;
  float4 v0 = *(const float4*)hr;
  float4 v1 = *(const float4*)(hr + 4);
  float s = v0.x + v0.y + v0.z + v0.w + v1.x + v1.y + v1.z + v1.w;
  float q = v0.x * v0.x + v0.y * v0.y + v0.z * v0.z + v0.w * v0.w
          + v1.x * v1.x + v1.y * v1.y + v1.z * v1.z + v1.w * v1.w;
  #pragma unroll
  for (int o = 1; o < 64; o <<= 1) { s += __shfl_xor(s, o); q += __shfl_xor(q, o); }
  float mean = s * (1.f / 512.f);
  float var = q * (1.f / 512.f) - mean * mean;
  float rstd = rsqrtf(var + 1e-5f);
  float4 g0 = *(const float4*)(g + lane * 8);
  float4 g1 = *(const float4*)(g + lane * 8 + 4);
  float4 b0v = *(const float4*)(bta + lane * 8);
  float4 b1v = *(const float4*)(bta + lane * 8 + 4);
  bf16x8 o8;
  o8[0] = (__bf16)__float2bfloat16((v0.x - mean) * rstd * g0.x + b0v.x);
  o8[1] = (__bf16)__float2bfloat16((v0.y - mean) * rstd * g0.y + b0v.y);
  o8[2] = (__bf16)__float2bfloat16((v0.z - mean) * rstd * g0.z + b0v.z);
  o8[3] = (__bf16)__float2bfloat16((v0.w - mean) * rstd * g0.w + b0v.w);
  o8[4] = (__bf16)__float2bfloat16((v1.x - mean) * rstd * g1.x + b1v.x);
  o8[5] = (__bf16)__float2bfloat16((v1.y - mean) * rstd * g1.y + b1v.y);
  o8[6] = (__bf16)__float2bfloat16((v1.z - mean) * rstd * g1.z + b1v.z);
  o8[7] = (__bf16)__float2bfloat16((v1.w - mean) * rstd * g1.w + b1v.w);
  *(bf16x8*)(out + ((size_t)(row >> 4) * 16 + (lane >> 2)) * 512 + (row & 15) * 8 + 128 * (lane & 3)) = o8;
}

// ---------------- frag GEMM: C[M,N] = A * BT^T + bias ----------------
// 128x128 block tile, 4 waves (64x64 each). 2-buf LDS + __syncthreads per K-step.
// C^T accumulation: acc = mfma(bg, af, acc) -> l15 = row, quad*4+r = col.
// MODE 0: out bf16 frag-tiled (KT_out = N/32).
// MODE 1: out fp32 row-major = resid + acc + bias (N==512==biasN).
// MODE 2: ReGLU pairs thread-local, out bf16 frag-tiled [M/16][(N/2)/32][512].
// MODE 3: MODE 1 + CLS rows (m%129==0) also written to outp2.
template <int MODE>
__global__ __launch_bounds__(256, 4) void gemm_frag(const bf16_t* __restrict__ A,
    const bf16_t* __restrict__ BT, const float* __restrict__ bias, int biasN,
    const float* __restrict__ resid, void* __restrict__ outp,
    float* __restrict__ outp2, int K, int N)
{
  __shared__ bf16_t lsA[2][8][512];   // 16 KB
  __shared__ bf16_t lsB[2][8][512];   // 16 KB

  // XCD-aware remap: blocks with lin%8==x get a contiguous idx chunk
  const int total = gridDim.x * gridDim.y;
  const int lin = blockIdx.y * gridDim.x + blockIdx.x;
  const int xcd = lin & 7, kb2 = lin >> 3;
  const int qch = total >> 3, rch = total & 7;
  const int idx = xcd * qch + (xcd < rch ? xcd : rch) + kb2;
  const int bm = idx / gridDim.x;
  const int bn = idx - bm * gridDim.x;
  const int m0 = bm * 128, n0 = bn * 128;

  const int tid = threadIdx.x;
  const int w = tid >> 6, l = tid & 63, l15 = l & 15, quad = l >> 4;
  const int wm = (w >> 1) * 64, wn = (w & 1) * 64;
  const int KT = K >> 5;

  const bf16_t* gA0 = A  + ((size_t)((m0 >> 4) + 2 * w) * KT) * 512 + l * 8;
  const bf16_t* gA1 = gA0 + (size_t)KT * 512;
  const bf16_t* gB0 = BT + ((size_t)((n0 >> 4) + 2 * w) * KT) * 512 + l * 8;
  const bf16_t* gB1 = gB0 + (size_t)KT * 512;
  const int sa = w * 2;
  const int ra = (w >> 1) * 4;
  const int rb = (w & 1) * 4;

  auto stage = [&](int buf, int t) {
    const size_t go = (size_t)t * 512;
    gload_lds16(gA0 + go, &lsA[buf][sa][0]);
    gload_lds16(gA1 + go, &lsA[buf][sa + 1][0]);
    gload_lds16(gB0 + go, &lsB[buf][sa][0]);
    gload_lds16(gB1 + go, &lsB[buf][sa + 1][0]);
  };

  floatx4 z4 = {0.f, 0.f, 0.f, 0.f};
  floatx4 acc[4][4];
  #pragma unroll
  for (int i = 0; i < 4; i++)
    #pragma unroll
    for (int j = 0; j < 4; j++) acc[i][j] = z4;

  stage(0, 0);
  __syncthreads();   // compiler drains vmcnt(0) before barrier -> buf0 ready

  int cur = 0;
  for (int t = 0; t < KT; ++t) {
    if (t + 1 < KT) stage(cur ^ 1, t + 1);   // async DMA, in flight across this step
    bf16x8 af[4], bg[4];
    #pragma unroll
    for (int i = 0; i < 4; i++) {
      af[i] = *(const bf16x8*)&lsA[cur][ra + i][l * 8];
      bg[i] = *(const bf16x8*)&lsB[cur][rb + i][l * 8];
    }
    #pragma unroll
    for (int i = 0; i < 4; i++)
      #pragma unroll
      for (int j = 0; j < 4; j++)
        acc[i][j] = mfma16(bg[j], af[i], acc[i][j]);   // C^T
    __syncthreads();   // drains vmcnt (next buf staged) + guards buf reuse
    cur ^= 1;
  }

  // epilogue: thread owns rows m = m0+wm+i*16+l15, cols nb..nb+3 (consecutive)
  #pragma unroll
  for (int i = 0; i < 4; i++) {
    int m = m0 + wm + i * 16 + l15;
    #pragma unroll
    for (int j = 0; j < 4; j++) {
      int nb = n0 + wn + j * 16 + quad * 4;
      if (MODE == 2) {
        int c2b = nb >> 1;
        bf16x2 o2;
        #pragma unroll
        for (int u = 0; u < 2; u++) {
          int c2 = c2b + u;
          bool vld = (2 * c2 < biasN);
          float av = acc[i][j][2 * u]     + (vld ? bias[c2] : 0.f);
          float bv = acc[i][j][2 * u + 1] + (vld ? bias[682 + c2] : 0.f);
          o2[u] = (__bf16)__float2bfloat16(av * fmaxf(bv, 0.f));
        }
        *(bf16x2*)&((bf16_t*)outp)[frag_elem(m, c2b, (N >> 1) >> 5)] = o2;
      } else if (MODE == 1 || MODE == 3) {
        size_t idx2 = (size_t)m * N + nb;
        float4 rv = *(const float4*)(resid + idx2);
        float4 ov;
        ov.x = acc[i][j][0] + bias[nb + 0] + rv.x;
        ov.y = acc[i][j][1] + bias[nb + 1] + rv.y;
        ov.z = acc[i][j][2] + bias[nb + 2] + rv.z;
        ov.w = acc[i][j][3] + bias[nb + 3] + rv.w;
        *(float4*)((float*)outp + idx2) = ov;
        if (MODE == 3) {
          int bq = m / 129;
          if (bq * 129 == m)   // CLS row of batch bq
            *(float4*)(outp2 + (size_t)bq * 512 + nb) = ov;
        }
      } else {
        bf16x4 o4;
        #pragma unroll
        for (int r = 0; r < 4; r++) {
          float bv = (nb + r < biasN) ? bias[nb + r] : 0.f;
          o4[r] = (__bf16)__float2bfloat16(acc[i][j][r] + bv);
        }
        *(bf16x4*)&((bf16_t*)outp)[frag_elem(m, nb, N >> 5)] = o4;
      }
    }
  }
}

// ---------------- fused attention: one block per (batch, head) ----------------
// qkv frag-tiled over [M, 1536] (KT=48); head hh: q at col hh*192, k +64, v +128.
// LDS = 20480 (vt) + 20480 (sc, p overlays) = 40960 B EXACTLY -> 4 blocks/CU.
constexpr int SP = 160;  // S=129 padded to 5*32
__global__ __launch_bounds__(256) void attn_kernel(const bf16_t* __restrict__ qkv,
                                                   bf16_t* __restrict__ attnout)
{
  __shared__ bf16_t vt_lds[64 * SP];   // [d][s_kv]
  __shared__ float sc[32 * SP];        // scores; p (bf16) overlays
  bf16_t* p_lds = (bf16_t*)sc;
  __bf16* vt_raw = (__bf16*)vt_lds;

  const int bh = blockIdx.x, b = bh >> 3, hh = bh & 7;
  const int tid = threadIdx.x;
  const int w = tid >> 6, l = tid & 63, l15 = l & 15, quad = l >> 4;
  const int rbase = b * 129;

  for (int i = tid; i < SP * 64 / 2; i += 256) ((unsigned int*)vt_lds)[i] = 0u;
  __syncthreads();
  for (int c = tid; c < 129 * 8; c += 256) {
    int s = c >> 3, ch = c & 7;
    bf16x8 tv = *(const bf16x8*)(qkv + frag_chunk(rbase + s, hh * 192 + 128 + ch * 8, 48));
    #pragma unroll
    for (int j = 0; j < 8; j++) vt_raw[(size_t)(ch * 8 + j) * SP + s] = tv[j];
  }
  __syncthreads();

  for (int qt = 0; qt < 5; qt++) {
    bf16x8 zq = {};
    bf16x8 aq[2][2];
    #pragma unroll
    for (int mt = 0; mt < 2; mt++) {
      int m = qt * 32 + mt * 16 + l15;
      #pragma unroll
      for (int t = 0; t < 2; t++)
        aq[mt][t] = (m < 129)
            ? *(const bf16x8*)(qkv + frag_chunk(rbase + m, hh * 192 + t * 32 + quad * 8, 48)) : zq;
    }
    for (int nt = w; nt < 10; nt += 4) {
      int krow = nt * 16 + l15;
      floatx4 a0 = {0.f, 0.f, 0.f, 0.f}, a1 = {0.f, 0.f, 0.f, 0.f};
      #pragma unroll
      for (int t = 0; t < 2; t++) {
        bf16x8 kf = (krow < 129)
            ? *(const bf16x8*)(qkv + frag_chunk(rbase + krow, hh * 192 + 64 + t * 32 + quad * 8, 48))
            : zq;
        a0 = mfma16(aq[0][t], kf, a0);
        a1 = mfma16(aq[1][t], kf, a1);
      }
      #pragma unroll
      for (int r = 0; r < 4; r++) {
        sc[(quad * 4 + r) * SP + nt * 16 + l15]      = a0[r] * SQRT_EMB_F;
        sc[(16 + quad * 4 + r) * SP + nt * 16 + l15] = a1[r] * SQRT_EMB_F;
      }
    }
    __syncthreads();

    // double softmax, 8 threads per row.
    // Pass 2 uses the analytic max: u = exp(s-m1), Z1 = sum u -> max(p1) = 1/Z1
    // exactly (argmax term e^0/Z1), so w = exp((u-1)*invZ1), out = w/sum(w).
    {
      int row = tid >> 3, sub = tid & 7;
      float vv[20];
      float mx = -1e30f;
      #pragma unroll
      for (int c = 0; c < 20; c++) {
        int j = sub + c * 8;
        vv[c] = (j < 129) ? sc[row * SP + j] : -1e30f;
        mx = fmaxf(mx, vv[c]);
      }
      #pragma unroll
      for (int o = 1; o < 8; o <<= 1) mx = fmaxf(mx, __shfl_xor(mx, o, 8));
      float sum = 0.f;
      #pragma unroll
      for (int c = 0; c < 20; c++) {
        int j = sub + c * 8;
        vv[c] = (j < 129) ? __expf(vv[c] - mx) : 0.f;
        sum += vv[c];
      }
      #pragma unroll
      for (int o = 1; o < 8; o <<= 1) sum += __shfl_xor(sum, o, 8);
      float inv = 1.f / sum;   // = max(p1) and the 1/Z1 scale
      float sum2 = 0.f;
      #pragma unroll
      for (int c = 0; c < 20; c++) {
        int j = sub + c * 8;
        vv[c] = (j < 129) ? __expf((vv[c] - 1.f) * inv) : 0.f;
        sum2 += vv[c];
      }
      #pragma unroll
      for (int o = 1; o < 8; o <<= 1) sum2 += __shfl_xor(sum2, o, 8);
      float inv2 = 1.f / sum2;
      __syncthreads();   // alias guard: all sc reads done before p overwrites
      #pragma unroll
      for (int c = 0; c < 20; c++) {
        int j = sub + c * 8;
        p_lds[row * SP + j] = __float2bfloat16(vv[c] * inv2);  // pads -> 0
      }
    }
    __syncthreads();

    // PV: o[32,64] = p[32,160] @ v[160,64]; store attno in frag layout (KT=16)
    {
      int mt = w >> 1, nt0 = (w & 1) * 2;
      floatx4 oacc[2];
      oacc[0] = floatx4{0.f, 0.f, 0.f, 0.f};
      oacc[1] = floatx4{0.f, 0.f, 0.f, 0.f};
      #pragma unroll
      for (int t = 0; t < 5; t++) {
        bf16x8 pf = *(const bf16x8*)&p_lds[(mt * 16 + l15) * SP + t * 32 + quad * 8];
        #pragma unroll
        for (int n = 0; n < 2; n++) {
          bf16x8 vf = *(const bf16x8*)&vt_lds[((nt0 + n) * 16 + l15) * SP + t * 32 + quad * 8];
          oacc[n] = mfma16(pf, vf, oacc[n]);
        }
      }
      #pragma unroll
      for (int n = 0; n < 2; n++)
        #pragma unroll
        for (int r = 0; r < 4; r++) {
          int sq = qt * 32 + mt * 16 + quad * 4 + r;
          if (sq < 129) {
            int cc = hh * 64 + (nt0 + n) * 16 + l15;
            attnout[frag_elem(rbase + sq, cc, 16)] = __float2bfloat16(oacc[n][r]);
          }
        }
    }
    __syncthreads();
  }
}

// ---------------- host launcher ----------------
extern "C" void kernel_launch(void* const* d_in, const int* in_sizes, int n_in,
                              void* d_out, int out_size, void* d_ws, size_t ws_size,
                              hipStream_t stream)
{
  const float* x       = (const float*)d_in[0];
  const float* tok_w   = (const float*)d_in[1];
  const float* tok_b   = (const float*)d_in[2];
  const float* cat_emb = (const float*)d_in[3];
  const float* Wqkv    = (const float*)d_in[4];
  const float* bqkv    = (const float*)d_in[5];
  const float* Wout    = (const float*)d_in[6];
  const float* bout    = (const float*)d_in[7];
  const float* W0      = (const float*)d_in[8];
  const float* b0      = (const float*)d_in[9];
  const float* W1      = (const float*)d_in[10];
  const float* b1      = (const float*)d_in[11];
  const float* ln0_g   = (const float*)d_in[12];
  const float* ln0_b   = (const float*)d_in[13];
  const float* ln1_g   = (const float*)d_in[14];
  const float* ln1_b   = (const float*)d_in[15];

  size_t off = 0;
  char* base = (char*)d_ws;
  auto alloc = [&](size_t n) { char* p = base + off; off += (n + 255) & ~(size_t)255; return p; };
  float*  h     = (float*) alloc((size_t)M_ROWS * 512 * 4);
  bf16_t* ab    = (bf16_t*)alloc((size_t)M_ROWS * 512 * 2);   // LN out, frag KT=16
  bf16_t* qkv   = (bf16_t*)alloc((size_t)M_ROWS * 1536 * 2);  // frag KT=48
  bf16_t* attno = (bf16_t*)alloc((size_t)M_ROWS * 512 * 2);   // frag KT=16
  bf16_t* regl  = (bf16_t*)alloc((size_t)M_ROWS * 704 * 2);   // frag KT=22
  bf16_t* WqkvT = (bf16_t*)alloc((size_t)6 * 1536 * 512 * 2);
  bf16_t* WoutT = (bf16_t*)alloc((size_t)6 * 512 * 512 * 2);
  bf16_t* W0T   = (bf16_t*)alloc((size_t)6 * 1408 * 512 * 2);  // pair-interleaved
  bf16_t* W1T   = (bf16_t*)alloc((size_t)6 * 512 * 704 * 2);
  (void)ws_size; (void)in_sizes; (void)n_in; (void)out_size;

  dim3 tb(32, 8, 1);
  transpose_cvt<0><<<dim3(16, 48, 6), tb, 0, stream>>>(Wqkv, WqkvT, 512, 1536, 512, 1536);
  transpose_cvt<0><<<dim3(16, 16, 6), tb, 0, stream>>>(Wout, WoutT, 512, 512, 512, 512);
  transpose_cvt<1><<<dim3(16, 44, 6), tb, 0, stream>>>(W0, W0T, 512, 1364, 512, 1408);
  transpose_cvt<0><<<dim3(22, 16, 6), tb, 0, stream>>>(W1, W1T, 682, 512, 704, 512);

  tokenizer_kernel<<<M_ROWS / 4, 256, 0, stream>>>(x, tok_w, tok_b, cat_emb, h, ab);

  for (int i = 0; i < 6; i++) {
    if (i)
      ln_kernel<<<M_ROWS / 4, 256, 0, stream>>>(h, ab, ln0_g + (size_t)i * 512,
                                                ln0_b + (size_t)i * 512);
    gemm_frag<0><<<dim3(12, 129), 256, 0, stream>>>(
        ab, WqkvT + (size_t)i * 1536 * 512, bqkv + (size_t)i * 1536, 1536, nullptr,
        qkv, nullptr, 512, 1536);
    attn_kernel<<<1024, 256, 0, stream>>>(qkv, attno);
    gemm_frag<1><<<dim3(4, 129), 256, 0, stream>>>(
        attno, WoutT + (size_t)i * 512 * 512, bout + (size_t)i * 512, 512, h,
        h, nullptr, 512, 512);
    ln_kernel<<<M_ROWS / 4, 256, 0, stream>>>(h, ab, ln1_g + (size_t)i * 512,
                                              ln1_b + (size_t)i * 512);
    gemm_frag<2><<<dim3(11, 129), 256, 0, stream>>>(
        ab, W0T + (size_t)i * 1408 * 512, b0 + (size_t)i * 1364, 1364, nullptr,
        regl, nullptr, 512, 1408);
    if (i < 5)
      gemm_frag<1><<<dim3(4, 129), 256, 0, stream>>>(
          regl, W1T + (size_t)i * 512 * 704, b1 + (size_t)i * 512, 512, h,
          h, nullptr, 704, 512);
    else
      gemm_frag<3><<<dim3(4, 129), 256, 0, stream>>>(
          regl, W1T + (size_t)i * 512 * 704, b1 + (size_t)i * 512, 512, h,
          h, (float*)d_out, 704, 512);
  }
}